// Round 4
// baseline (1276.885 us; speedup 1.0000x reference)
//
#include <hip/hip_runtime.h>
#include <cstdint>
#include <cstddef>

// ---------------------------------------------------------------------------
// EncoderBlock: S=4096, E=2048, H=8192, fp32 in/out, bf16 MFMA internally.
// m97-style GEMM: 128x128 tile, BK=32, 4 waves x 4x4 mfma_f32_16x16x32_bf16,
// global_load_lds width=16, 2-barrier K-loop. All GEMMs C = A @ B^T.
// R2: fused QKV GEMM (1536 blocks), split-K=2 FFN2 (1024 blocks) + combine.
// R3: fix R2 crash — workspace repacked to 240 MB peak (proven <248 MB fits);
//     transpose_bf16 LDS row stride padded to 68 (8B-aligned ds_write_b64);
//     fp32 h dropped (residual uses bf16 hb; error budget ok).
// ---------------------------------------------------------------------------

constexpr int S = 4096;
constexpr int E = 2048;
constexpr int H = 8192;

typedef __bf16 bf16;
typedef bf16  bf16x8 __attribute__((ext_vector_type(8)));
typedef bf16  bf16x4 __attribute__((ext_vector_type(4)));
typedef float f32x4  __attribute__((ext_vector_type(4)));

typedef __attribute__((address_space(1))) void as1_void;
typedef __attribute__((address_space(3))) void as3_void;

__device__ __forceinline__ void ldg2lds16(const void* g, void* l) {
  __builtin_amdgcn_global_load_lds((as1_void*)g, (as3_void*)l, 16, 0, 0);
}

// ---------------------------------------------------------------------------
// GEMM: C[M,N] = A[M,K] @ Bt[N,K]^T  (row strides lda/ldb/ldc). Epilogues:
// EPI 2: out bf16 = acc * scale                       (scores)
// EPI 3: out f32  = acc + add, fused LN sums          (attn residual)
// EPI 4: out bf16 = relu(acc + bias[col])             (FFN act)
// EPI 6: out bf16 = acc + {bq|bk|bv}[col&2047]        (fused QKV)
// EPI 7: out f32  = acc, split-K partial: z=blockIdx.z K-window, Cf+z*M*N
// Requires gridDim.x % 8 == 0 and gridDim.y % 8 == 0.
// ---------------------------------------------------------------------------
template <int EPI>
__global__ __launch_bounds__(256)
void gemm_bt(const bf16* __restrict__ A, int lda,
             const bf16* __restrict__ Bt, int ldb,
             bf16* __restrict__ Cb, float* __restrict__ Cf, int ldc,
             const float* __restrict__ bias, const float* __restrict__ bias2,
             const float* __restrict__ bias3, const float* __restrict__ add,
             float* __restrict__ red, int M, int N, int K, float scale)
{
  __shared__ bf16 sA[128 * 32];
  __shared__ bf16 sB[128 * 32];

  const int tid  = threadIdx.x;
  const int lane = tid & 63;
  const int wave = tid >> 6;

  if (EPI == 7) {
    const int z = blockIdx.z;
    A  += (size_t)z * K;
    Bt += (size_t)z * K;
    Cf += (size_t)z * M * N;
  }

  const int ntiles = gridDim.x;
  const int b      = blockIdx.y * ntiles + blockIdx.x;
  const int group  = b >> 6;
  const int within = b & 63;
  const int gpr    = ntiles >> 3;
  const int m0 = ((group / gpr) * 8 + (within >> 3)) * 128;
  const int n0 = ((group % gpr) * 8 + (within & 7)) * 128;

  const int wm = (wave & 1) * 64;
  const int wn = (wave >> 1) * 64;

  const int sr = tid >> 2;
  const int sc = (tid & 3) * 8;
  const bf16* gA  = A  + (size_t)(m0 + sr) * lda + sc;
  const bf16* gA2 = gA + (size_t)64 * lda;
  const bf16* gB  = Bt + (size_t)(n0 + sr) * ldb + sc;
  const bf16* gB2 = gB + (size_t)64 * ldb;
  bf16* lA  = &sA[tid * 8];
  bf16* lA2 = lA + 64 * 32;
  bf16* lB  = &sB[tid * 8];
  bf16* lB2 = lB + 64 * 32;

  const int fr = lane & 15;
  const int fq = lane >> 4;
  const bf16* rA = &sA[(wm + fr) * 32 + fq * 8];
  const bf16* rB = &sB[(wn + fr) * 32 + fq * 8];

  f32x4 acc[4][4] = {};

  for (int k0 = 0; k0 < K; k0 += 32) {
    ldg2lds16(gA, lA);
    ldg2lds16(gA2, lA2);
    ldg2lds16(gB, lB);
    ldg2lds16(gB2, lB2);
    gA += 32; gA2 += 32; gB += 32; gB2 += 32;
    __syncthreads();

    bf16x8 a[4], b8[4];
#pragma unroll
    for (int i = 0; i < 4; ++i) a[i]  = *(const bf16x8*)(rA + i * 16 * 32);
#pragma unroll
    for (int j = 0; j < 4; ++j) b8[j] = *(const bf16x8*)(rB + j * 16 * 32);
#pragma unroll
    for (int i = 0; i < 4; ++i)
#pragma unroll
      for (int j = 0; j < 4; ++j)
        acc[i][j] = __builtin_amdgcn_mfma_f32_16x16x32_bf16(a[i], b8[j], acc[i][j], 0, 0, 0);
    __syncthreads();
  }

  // C/D layout (16x16x32): row = (lane>>4)*4 + reg, col = lane&15
  const int er = m0 + wm + fq * 4;
  const int ec = n0 + wn + fr;
  const float* bb = nullptr;
  if (EPI == 6) bb = (n0 < 2048) ? bias : (n0 < 4096) ? bias2 : bias3;
  float ls = 0.f, ls2 = 0.f;
#pragma unroll
  for (int i = 0; i < 4; ++i) {
#pragma unroll
    for (int r = 0; r < 4; ++r) {
      const int gr = er + i * 16 + r;
#pragma unroll
      for (int j = 0; j < 4; ++j) {
        const int gc = ec + j * 16;
        const size_t idx = (size_t)gr * ldc + gc;
        float v = acc[i][j][r];
        if (EPI == 2) {
          Cb[idx] = (bf16)(v * scale);
        } else if (EPI == 3) {
          v += add[idx];
          Cf[idx] = v; ls += v; ls2 += v * v;
        } else if (EPI == 4) {
          v += bias[gc];
          v = v > 0.f ? v : 0.f;
          Cb[idx] = (bf16)v;
        } else if (EPI == 6) {
          v += bb[gc & 2047];
          Cb[idx] = (bf16)v;
        } else {  // EPI == 7
          Cf[idx] = v;
        }
      }
    }
  }

  if (EPI == 3) {
#pragma unroll
    for (int o = 32; o; o >>= 1) {
      ls  += __shfl_xor(ls,  o, 64);
      ls2 += __shfl_xor(ls2, o, 64);
    }
    float* sred = (float*)sA;
    if (lane == 0) { sred[wave * 2] = ls; sred[wave * 2 + 1] = ls2; }
    __syncthreads();
    if (tid == 0) {
      atomicAdd(red,     sred[0] + sred[2] + sred[4] + sred[6]);
      atomicAdd(red + 1, sred[1] + sred[3] + sred[5] + sred[7]);
    }
  }
}

// ---------------------------------------------------------------------------
__global__ __launch_bounds__(256)
void cvt_f32_bf16(const float* __restrict__ src, bf16* __restrict__ dst)
{
  const size_t i = ((size_t)blockIdx.x * 256 + threadIdx.x) * 4;
  const float4 t = *(const float4*)(src + i);
  bf16x4 b;
  b[0] = (bf16)t.x; b[1] = (bf16)t.y; b[2] = (bf16)t.z; b[3] = (bf16)t.w;
  *(bf16x4*)(dst + i) = b;
}

// fp32 [R,C] -> bf16 [C,R]
__global__ __launch_bounds__(256)
void transpose_cvt(const float* __restrict__ src, bf16* __restrict__ dst, int R, int C)
{
  __shared__ float tile[32][33];
  const int c0 = blockIdx.x * 32, r0 = blockIdx.y * 32;
  const int tx = threadIdx.x & 31, ty = threadIdx.x >> 5;
#pragma unroll
  for (int rr = ty; rr < 32; rr += 8)
    tile[rr][tx] = src[(size_t)(r0 + rr) * C + (c0 + tx)];
  __syncthreads();
#pragma unroll
  for (int rr = ty; rr < 32; rr += 8)
    dst[(size_t)(c0 + rr) * R + (r0 + tx)] = (bf16)tile[tx][rr];
}

// bf16 [R,C] (row stride ls) -> bf16 [C,R] (row stride ld), 64x64 tiles.
// LDS row stride 68 bf16 = 136 B (8B-aligned for ds_write_b64).
__global__ __launch_bounds__(256)
void transpose_bf16(const bf16* __restrict__ src, bf16* __restrict__ dst,
                    int ls, int ld)
{
  __shared__ bf16 t[64][68];
  const int r0 = blockIdx.y * 64, c0 = blockIdx.x * 64;
  const int tx = threadIdx.x & 15;
  const int ty = threadIdx.x >> 4;
#pragma unroll
  for (int p = 0; p < 4; ++p) {
    const int r = ty + p * 16;
    *(bf16x4*)&t[r][tx * 4] = *(const bf16x4*)(src + (size_t)(r0 + r) * ls + c0 + tx * 4);
  }
  __syncthreads();
#pragma unroll
  for (int p = 0; p < 4; ++p) {
    const int c = ty + p * 16;
    bf16x4 v;
#pragma unroll
    for (int i = 0; i < 4; ++i) v[i] = t[tx * 4 + i][c];
    *(bf16x4*)(dst + (size_t)(c0 + c) * ld + r0 + tx * 4) = v;
  }
}

// ---------------------------------------------------------------------------
__global__ __launch_bounds__(256)
void softmax_rows(bf16* __restrict__ P)
{
  const int row  = blockIdx.x;
  bf16* p = P + (size_t)row * 4096;
  const int tid  = threadIdx.x;
  const int lane = tid & 63, wave = tid >> 6;

  bf16x8 c0 = *(const bf16x8*)(p + tid * 16);
  bf16x8 c1 = *(const bf16x8*)(p + tid * 16 + 8);
  float v[16];
#pragma unroll
  for (int i = 0; i < 8; ++i) { v[i] = (float)c0[i]; v[8 + i] = (float)c1[i]; }

  float m = v[0];
#pragma unroll
  for (int i = 1; i < 16; ++i) m = fmaxf(m, v[i]);
#pragma unroll
  for (int o = 32; o; o >>= 1) m = fmaxf(m, __shfl_xor(m, o, 64));
  __shared__ float sred[8];
  if (lane == 0) sred[wave] = m;
  __syncthreads();
  m = fmaxf(fmaxf(sred[0], sred[1]), fmaxf(sred[2], sred[3]));

  float s = 0.f;
#pragma unroll
  for (int i = 0; i < 16; ++i) { v[i] = __expf(v[i] - m); s += v[i]; }
#pragma unroll
  for (int o = 32; o; o >>= 1) s += __shfl_xor(s, o, 64);
  if (lane == 0) sred[4 + wave] = s;
  __syncthreads();
  s = sred[4] + sred[5] + sred[6] + sred[7];

  const float inv = 1.f / s;
  bf16x8 o0, o1;
#pragma unroll
  for (int i = 0; i < 8; ++i) { o0[i] = (bf16)(v[i] * inv); o1[i] = (bf16)(v[8 + i] * inv); }
  *(bf16x8*)(p + tid * 16)     = o0;
  *(bf16x8*)(p + tid * 16 + 8) = o1;
}

// ---------------------------------------------------------------------------
// split-K combine: y2 = p0 + p1 + b2[col] + hb (bf16->f32), fused LN sums
// ---------------------------------------------------------------------------
__global__ __launch_bounds__(256)
void combine_ffn(const float* __restrict__ p0, const float* __restrict__ p1,
                 const bf16* __restrict__ hb, const float* __restrict__ b2,
                 float* __restrict__ y, float* __restrict__ red)
{
  const int tid = threadIdx.x;
  const int lane = tid & 63, wave = tid >> 6;
  const size_t i = ((size_t)blockIdx.x * 256 + tid) * 4;
  const float4 a  = *(const float4*)(p0 + i);
  const float4 b  = *(const float4*)(p1 + i);
  const bf16x4 hh = *(const bf16x4*)(hb + i);
  const float4 bb = *(const float4*)(b2 + (i & 2047));
  float4 v;
  v.x = a.x + b.x + (float)hh[0] + bb.x;
  v.y = a.y + b.y + (float)hh[1] + bb.y;
  v.z = a.z + b.z + (float)hh[2] + bb.z;
  v.w = a.w + b.w + (float)hh[3] + bb.w;
  *(float4*)(y + i) = v;

  float ls  = v.x + v.y + v.z + v.w;
  float ls2 = v.x * v.x + v.y * v.y + v.z * v.z + v.w * v.w;
#pragma unroll
  for (int o = 32; o; o >>= 1) {
    ls  += __shfl_xor(ls,  o, 64);
    ls2 += __shfl_xor(ls2, o, 64);
  }
  __shared__ float sred[8];
  if (lane == 0) { sred[wave * 2] = ls; sred[wave * 2 + 1] = ls2; }
  __syncthreads();
  if (tid == 0) {
    atomicAdd(red,     sred[0] + sred[2] + sred[4] + sred[6]);
    atomicAdd(red + 1, sred[1] + sred[3] + sred[5] + sred[7]);
  }
}

// ---------------------------------------------------------------------------
__global__ void ln_finalize(float* red, float n)
{
  const float mu  = red[0] / n;
  const float var = red[1] / n - mu * mu;
  red[2] = mu;
  red[3] = rsqrtf(var + 1e-5f);
}

// of and ob each nullable
__global__ __launch_bounds__(256)
void ln_apply(const float* __restrict__ y, const float* __restrict__ red,
              float* __restrict__ of, bf16* __restrict__ ob)
{
  const float mu = red[2], rs = red[3];
  const size_t i = ((size_t)blockIdx.x * 256 + threadIdx.x) * 4;
  float4 t = *(const float4*)(y + i);
  t.x = (t.x - mu) * rs; t.y = (t.y - mu) * rs;
  t.z = (t.z - mu) * rs; t.w = (t.w - mu) * rs;
  if (of) *(float4*)(of + i) = t;
  if (ob) {
    bf16x4 b;
    b[0] = (bf16)t.x; b[1] = (bf16)t.y; b[2] = (bf16)t.z; b[3] = (bf16)t.w;
    *(bf16x4*)(ob + i) = b;
  }
}

// ---------------------------------------------------------------------------
extern "C" void kernel_launch(void* const* d_in, const int* in_sizes, int n_in,
                              void* d_out, int out_size, void* d_ws, size_t ws_size,
                              hipStream_t stream)
{
  const float* x  = (const float*)d_in[0];
  const float* Wq = (const float*)d_in[1];
  const float* bq = (const float*)d_in[2];
  const float* Wk = (const float*)d_in[3];
  const float* bk = (const float*)d_in[4];
  const float* Wv = (const float*)d_in[5];
  const float* bv = (const float*)d_in[6];
  const float* W1 = (const float*)d_in[7];
  const float* b1 = (const float*)d_in[8];
  const float* W2 = (const float*)d_in[9];
  const float* b2 = (const float*)d_in[10];
  float* out = (float*)d_out;

  const size_t MB = 1ull << 20;
  char* ws = (char*)d_ws;

  // Liveness-packed layout, 240 MB peak (<248 MB proven to fit):
  //   0- 16: xb (x bf16); after LN1, hb (h bf16) in place
  //  16- 48: W1T                  (dead after FFN1)
  //  48- 80: W2T                  (dead after FFN2)
  //  80-104: WqkvT                (dead after QKV GEMM)
  // 104-152: QKVb                 (dead after scores GEMM)
  // 152-168: VbT                  (dead after attn GEMM)
  // 168-200: Pb                   (dead after attn GEMM)
  // 200-232: y (attn+x fp32)      (dead after ln_apply1)
  //  80-144: act (FFN1 out)       (over WqkvT+QKVb, both dead by then)
  // 144-208: p0|p1 split-K partials (over VbT+Pb+part of y region order:
  //          written in FFN2, when VbT/Pb/y all dead)
  // 208-240: y2 (combine out)
  // 240+   : red (8 floats)
  bf16*  xb    = (bf16*)(ws);
  bf16*  hb    = xb;
  bf16*  W1T   = (bf16*)(ws + 16 * MB);
  bf16*  W2T   = (bf16*)(ws + 48 * MB);
  bf16*  WqkvT = (bf16*)(ws + 80 * MB);
  bf16*  QKVb  = (bf16*)(ws + 104 * MB);
  bf16*  VbT   = (bf16*)(ws + 152 * MB);
  bf16*  Pb    = (bf16*)(ws + 168 * MB);
  float* y     = (float*)(ws + 200 * MB);
  bf16*  act   = (bf16*)(ws + 80 * MB);
  float* p0    = (float*)(ws + 144 * MB);
  float* p1    = p0 + (size_t)S * E;          // ws + 176 MB
  float* y2    = (float*)(ws + 208 * MB);
  float* red   = (float*)(ws + 240 * MB);

  hipMemsetAsync(red, 0, 32, stream);

  const dim3 blk(256);
  const int nElemBlocks = (S * E) / 1024;

  cvt_f32_bf16<<<dim3(nElemBlocks), blk, 0, stream>>>(x, xb);
  transpose_cvt<<<dim3(E / 32, E / 32), blk, 0, stream>>>(Wq, WqkvT, E, E);
  transpose_cvt<<<dim3(E / 32, E / 32), blk, 0, stream>>>(Wk, WqkvT + (size_t)E * E, E, E);
  transpose_cvt<<<dim3(E / 32, E / 32), blk, 0, stream>>>(Wv, WqkvT + 2 * (size_t)E * E, E, E);
  transpose_cvt<<<dim3(H / 32, E / 32), blk, 0, stream>>>(W1, W1T, E, H);
  transpose_cvt<<<dim3(E / 32, H / 32), blk, 0, stream>>>(W2, W2T, H, E);

  // fused QKV: QKVb[S,3E] = xb @ WqkvT^T + [bq|bk|bv]  (1536 blocks)
  gemm_bt<6><<<dim3(3 * E / 128, S / 128), blk, 0, stream>>>(
      xb, E, WqkvT, E, QKVb, nullptr, 3 * E, bq, bk, bv, nullptr, nullptr, S, 3 * E, E, 0.f);

  // V^T[E,S] from QKVb cols [2E,3E)
  transpose_bf16<<<dim3(E / 64, S / 64), blk, 0, stream>>>(QKVb + 2 * E, VbT, 3 * E, S);

  // scores = (Q @ K^T)/64 -> bf16, softmax rows
  gemm_bt<2><<<dim3(S / 128, S / 128), blk, 0, stream>>>(
      QKVb, 3 * E, QKVb + E, 3 * E, Pb, nullptr, S, nullptr, nullptr, nullptr, nullptr, nullptr,
      S, S, E, 1.0f / 64.0f);
  softmax_rows<<<dim3(S), blk, 0, stream>>>(Pb);

  // y = x + P @ V (fp32, fused LN1 sums)
  gemm_bt<3><<<dim3(E / 128, S / 128), blk, 0, stream>>>(
      Pb, S, VbT, S, nullptr, y, E, nullptr, nullptr, nullptr, x, red, S, E, S, 0.f);
  ln_finalize<<<1, 1, 0, stream>>>(red, (float)((size_t)S * E));
  ln_apply<<<dim3(nElemBlocks), blk, 0, stream>>>(y, red, nullptr, hb);

  // act = relu(h @ W1 + b1) -> bf16  (2048 blocks)
  gemm_bt<4><<<dim3(H / 128, S / 128), blk, 0, stream>>>(
      hb, E, W1T, E, act, nullptr, H, b1, nullptr, nullptr, nullptr, nullptr, S, H, E, 0.f);

  // FFN2 split-K=2 -> p0,p1 (1024 blocks), combine + LN2
  gemm_bt<7><<<dim3(E / 128, S / 128, 2), blk, 0, stream>>>(
      act, H, W2T, H, nullptr, p0, E, nullptr, nullptr, nullptr, nullptr, nullptr,
      S, E, H / 2, 0.f);
  combine_ffn<<<dim3(nElemBlocks), blk, 0, stream>>>(p0, p1, hb, b2, y2, red + 4);
  ln_finalize<<<1, 1, 0, stream>>>(red + 4, (float)((size_t)S * E));
  ln_apply<<<dim3(nElemBlocks), blk, 0, stream>>>(y2, red + 4, out, nullptr);
}

// Round 5
// 901.456 us; speedup vs baseline: 1.4165x; 1.4165x over previous
//
#include <hip/hip_runtime.h>
#include <cstdint>
#include <cstddef>

// ---------------------------------------------------------------------------
// EncoderBlock: S=4096, E=2048, H=8192, fp32 in/out, bf16 MFMA internally.
// R4: R1 launch structure (separate Q,K,V^T GEMMs; fused FFN2) + new K-loop:
//   BK=64 (32 MFMA per barrier, halves barrier-drain count),
//   XOR bank-swizzle of 16B chunks (row stride 64 bf16 = 32 dwords would be
//   16-way bank-aliased; swizzle makes reads 2-way = free). Swizzle is done
//   on the GLOBAL source address, since global_load_lds LDS dest must stay
//   uniform-base + lane*16.
//   bf16 residual path (no fp32 h buffer) kept from R3.
// ---------------------------------------------------------------------------

constexpr int S = 4096;
constexpr int E = 2048;
constexpr int H = 8192;

typedef __bf16 bf16;
typedef bf16  bf16x8 __attribute__((ext_vector_type(8)));
typedef bf16  bf16x4 __attribute__((ext_vector_type(4)));
typedef float f32x4  __attribute__((ext_vector_type(4)));

typedef __attribute__((address_space(1))) void as1_void;
typedef __attribute__((address_space(3))) void as3_void;

__device__ __forceinline__ void ldg2lds16(const void* g, void* l) {
  __builtin_amdgcn_global_load_lds((as1_void*)g, (as3_void*)l, 16, 0, 0);
}

// ---------------------------------------------------------------------------
// GEMM: C[M,N] = A[M,K] @ Bt[N,K]^T  (row strides lda/ldb/ldc). Epilogues:
// EPI 0: out bf16 = acc + bias[col]                   (Q,K proj)
// EPI 1: out bf16 = acc + bias[row]                   (V^T proj)
// EPI 2: out bf16 = acc * scale                       (scores)
// EPI 3: out f32  = acc + add (f32), fused LN sums    (attn residual)
// EPI 4: out bf16 = relu(acc + bias[col])             (FFN act)
// EPI 5: out f32  = acc + bias[col] + addb (bf16), fused LN sums (FFN resid)
// Requires gridDim.x % 8 == 0, gridDim.y % 8 == 0, K % 64 == 0.
// ---------------------------------------------------------------------------
template <int EPI>
__global__ __launch_bounds__(256, 3)
void gemm_bt(const bf16* __restrict__ A, int lda,
             const bf16* __restrict__ Bt, int ldb,
             bf16* __restrict__ Cb, float* __restrict__ Cf, int ldc,
             const float* __restrict__ bias, const float* __restrict__ add,
             const bf16* __restrict__ addb,
             float* __restrict__ red, int M, int N, int K, float scale)
{
  __shared__ bf16 sA[128 * 64];   // 16 KB
  __shared__ bf16 sB[128 * 64];   // 16 KB

  const int tid  = threadIdx.x;
  const int lane = tid & 63;
  const int wave = tid >> 6;

  // 8x8 super-group swizzle (L2 locality; measured neutral, kept as harmless)
  const int ntiles = gridDim.x;
  const int b      = blockIdx.y * ntiles + blockIdx.x;
  const int group  = b >> 6;
  const int within = b & 63;
  const int gpr    = ntiles >> 3;
  const int m0 = ((group / gpr) * 8 + (within >> 3)) * 128;
  const int n0 = ((group % gpr) * 8 + (within & 7)) * 128;

  const int wm = (wave & 1) * 64;
  const int wn = (wave >> 1) * 64;

  // --- staging: 128 rows x 64 cols per operand, 4 issues of 32 rows ---
  // thread t covers row (t>>3), 16B chunk (t&7); global chunk index is
  // XOR-swizzled by (row&7) so LDS row r holds chunk c at slot c^(r&7).
  const int sr = tid >> 3;                         // 0..31
  const int gsw = ((tid & 7) ^ (sr & 7)) * 8;      // swizzled col offset (elems)
  const bf16* gA = A  + (size_t)(m0 + sr) * lda + gsw;
  const bf16* gB = Bt + (size_t)(n0 + sr) * ldb + gsw;
  const size_t a32 = (size_t)32 * lda;
  const size_t b32 = (size_t)32 * ldb;
  bf16* lA = &sA[tid * 8];
  bf16* lB = &sB[tid * 8];

  // --- MFMA fragment addressing (reader side of the swizzle) ---
  // lane = fq*16+fr needs row wm+fr+16i, cols fq*8+32*kk..+8.
  // chunk c = fq+4*kk; slot p = c ^ (fr&7); kk=1 slot = p0^4.
  const int fr = lane & 15;
  const int fq = lane >> 4;
  const int p0 = (fq ^ (fr & 7)) * 8;
  const int p1 = p0 ^ 32;                          // (c^4) * 8
  const bf16* rA = &sA[(wm + fr) * 64];
  const bf16* rB = &sB[(wn + fr) * 64];

  f32x4 acc[4][4] = {};

  for (int k0 = 0; k0 < K; k0 += 64) {
    ldg2lds16(gA,           lA);
    ldg2lds16(gA +     a32, lA + 32 * 64);
    ldg2lds16(gA + 2 * a32, lA + 64 * 64);
    ldg2lds16(gA + 3 * a32, lA + 96 * 64);
    ldg2lds16(gB,           lB);
    ldg2lds16(gB +     b32, lB + 32 * 64);
    ldg2lds16(gB + 2 * b32, lB + 64 * 64);
    ldg2lds16(gB + 3 * b32, lB + 96 * 64);
    gA += 64; gB += 64;
    __syncthreads();   // drains vmcnt(0): staged tiles visible

    bf16x8 a0[4], a1[4], b0[4], b1[4];
#pragma unroll
    for (int i = 0; i < 4; ++i) {
      a0[i] = *(const bf16x8*)(rA + i * 1024 + p0);
      a1[i] = *(const bf16x8*)(rA + i * 1024 + p1);
    }
#pragma unroll
    for (int j = 0; j < 4; ++j) {
      b0[j] = *(const bf16x8*)(rB + j * 1024 + p0);
      b1[j] = *(const bf16x8*)(rB + j * 1024 + p1);
    }
#pragma unroll
    for (int i = 0; i < 4; ++i)
#pragma unroll
      for (int j = 0; j < 4; ++j)
        acc[i][j] = __builtin_amdgcn_mfma_f32_16x16x32_bf16(a0[i], b0[j], acc[i][j], 0, 0, 0);
#pragma unroll
    for (int i = 0; i < 4; ++i)
#pragma unroll
      for (int j = 0; j < 4; ++j)
        acc[i][j] = __builtin_amdgcn_mfma_f32_16x16x32_bf16(a1[i], b1[j], acc[i][j], 0, 0, 0);
    __syncthreads();   // reads done before next iteration overwrites LDS
  }

  // epilogue: C/D layout (16x16x32): row = (lane>>4)*4 + reg, col = lane&15
  const int er = m0 + wm + fq * 4;
  const int ec = n0 + wn + fr;
  float ls = 0.f, ls2 = 0.f;
#pragma unroll
  for (int i = 0; i < 4; ++i) {
#pragma unroll
    for (int r = 0; r < 4; ++r) {
      const int gr = er + i * 16 + r;
#pragma unroll
      for (int j = 0; j < 4; ++j) {
        const int gc = ec + j * 16;
        const size_t idx = (size_t)gr * ldc + gc;
        float v = acc[i][j][r];
        if (EPI == 0) {
          v += bias[gc];
          Cb[idx] = (bf16)v;
        } else if (EPI == 1) {
          v += bias[gr];
          Cb[idx] = (bf16)v;
        } else if (EPI == 2) {
          Cb[idx] = (bf16)(v * scale);
        } else if (EPI == 3) {
          v += add[idx];
          Cf[idx] = v; ls += v; ls2 += v * v;
        } else if (EPI == 4) {
          v += bias[gc];
          v = v > 0.f ? v : 0.f;
          Cb[idx] = (bf16)v;
        } else {  // EPI == 5
          v += bias[gc] + (float)addb[idx];
          Cf[idx] = v; ls += v; ls2 += v * v;
        }
      }
    }
  }

  if (EPI == 3 || EPI == 5) {
#pragma unroll
    for (int o = 32; o; o >>= 1) {
      ls  += __shfl_xor(ls,  o, 64);
      ls2 += __shfl_xor(ls2, o, 64);
    }
    float* sred = (float*)sA;   // safe: all waves past final barrier
    if (lane == 0) { sred[wave * 2] = ls; sred[wave * 2 + 1] = ls2; }
    __syncthreads();
    if (tid == 0) {
      atomicAdd(red,     sred[0] + sred[2] + sred[4] + sred[6]);
      atomicAdd(red + 1, sred[1] + sred[3] + sred[5] + sred[7]);
    }
  }
}

// ---------------------------------------------------------------------------
__global__ __launch_bounds__(256)
void cvt_f32_bf16(const float* __restrict__ src, bf16* __restrict__ dst)
{
  const size_t i = ((size_t)blockIdx.x * 256 + threadIdx.x) * 4;
  const float4 t = *(const float4*)(src + i);
  bf16x4 b;
  b[0] = (bf16)t.x; b[1] = (bf16)t.y; b[2] = (bf16)t.z; b[3] = (bf16)t.w;
  *(bf16x4*)(dst + i) = b;
}

// fp32 [R,C] -> bf16 [C,R]
__global__ __launch_bounds__(256)
void transpose_cvt(const float* __restrict__ src, bf16* __restrict__ dst, int R, int C)
{
  __shared__ float tile[32][33];
  const int c0 = blockIdx.x * 32, r0 = blockIdx.y * 32;
  const int tx = threadIdx.x & 31, ty = threadIdx.x >> 5;
#pragma unroll
  for (int rr = ty; rr < 32; rr += 8)
    tile[rr][tx] = src[(size_t)(r0 + rr) * C + (c0 + tx)];
  __syncthreads();
#pragma unroll
  for (int rr = ty; rr < 32; rr += 8)
    dst[(size_t)(c0 + rr) * R + (r0 + tx)] = (bf16)tile[tx][rr];
}

// ---------------------------------------------------------------------------
__global__ __launch_bounds__(256)
void softmax_rows(bf16* __restrict__ P)
{
  const int row  = blockIdx.x;
  bf16* p = P + (size_t)row * 4096;
  const int tid  = threadIdx.x;
  const int lane = tid & 63, wave = tid >> 6;

  bf16x8 c0 = *(const bf16x8*)(p + tid * 16);
  bf16x8 c1 = *(const bf16x8*)(p + tid * 16 + 8);
  float v[16];
#pragma unroll
  for (int i = 0; i < 8; ++i) { v[i] = (float)c0[i]; v[8 + i] = (float)c1[i]; }

  float m = v[0];
#pragma unroll
  for (int i = 1; i < 16; ++i) m = fmaxf(m, v[i]);
#pragma unroll
  for (int o = 32; o; o >>= 1) m = fmaxf(m, __shfl_xor(m, o, 64));
  __shared__ float sred[8];
  if (lane == 0) sred[wave] = m;
  __syncthreads();
  m = fmaxf(fmaxf(sred[0], sred[1]), fmaxf(sred[2], sred[3]));

  float s = 0.f;
#pragma unroll
  for (int i = 0; i < 16; ++i) { v[i] = __expf(v[i] - m); s += v[i]; }
#pragma unroll
  for (int o = 32; o; o >>= 1) s += __shfl_xor(s, o, 64);
  if (lane == 0) sred[4 + wave] = s;
  __syncthreads();
  s = sred[4] + sred[5] + sred[6] + sred[7];

  const float inv = 1.f / s;
  bf16x8 o0, o1;
#pragma unroll
  for (int i = 0; i < 8; ++i) { o0[i] = (bf16)(v[i] * inv); o1[i] = (bf16)(v[8 + i] * inv); }
  *(bf16x8*)(p + tid * 16)     = o0;
  *(bf16x8*)(p + tid * 16 + 8) = o1;
}

// ---------------------------------------------------------------------------
__global__ void ln_finalize(float* red, float n)
{
  const float mu  = red[0] / n;
  const float var = red[1] / n - mu * mu;
  red[2] = mu;
  red[3] = rsqrtf(var + 1e-5f);
}

// of and ob each nullable
__global__ __launch_bounds__(256)
void ln_apply(const float* __restrict__ y, const float* __restrict__ red,
              float* __restrict__ of, bf16* __restrict__ ob)
{
  const float mu = red[2], rs = red[3];
  const size_t i = ((size_t)blockIdx.x * 256 + threadIdx.x) * 4;
  float4 t = *(const float4*)(y + i);
  t.x = (t.x - mu) * rs; t.y = (t.y - mu) * rs;
  t.z = (t.z - mu) * rs; t.w = (t.w - mu) * rs;
  if (of) *(float4*)(of + i) = t;
  if (ob) {
    bf16x4 b;
    b[0] = (bf16)t.x; b[1] = (bf16)t.y; b[2] = (bf16)t.z; b[3] = (bf16)t.w;
    *(bf16x4*)(ob + i) = b;
  }
}

// ---------------------------------------------------------------------------
extern "C" void kernel_launch(void* const* d_in, const int* in_sizes, int n_in,
                              void* d_out, int out_size, void* d_ws, size_t ws_size,
                              hipStream_t stream)
{
  const float* x  = (const float*)d_in[0];
  const float* Wq = (const float*)d_in[1];
  const float* bq = (const float*)d_in[2];
  const float* Wk = (const float*)d_in[3];
  const float* bk = (const float*)d_in[4];
  const float* Wv = (const float*)d_in[5];
  const float* bv = (const float*)d_in[6];
  const float* W1 = (const float*)d_in[7];
  const float* b1 = (const float*)d_in[8];
  const float* W2 = (const float*)d_in[9];
  const float* b2 = (const float*)d_in[10];
  float* out = (float*)d_out;

  const size_t MB = 1ull << 20;
  char* ws = (char*)d_ws;

  // Layout, 216 MB peak (248 MB proven safe in R0/R1):
  //   0- 16: xb (x bf16); after LN1, hb (h bf16) in place
  //  16- 24: WqT   24- 32: WkT   32- 40: WvT
  //  40- 72: W1T   72-104: W2T
  // 104-168: Qb(104-120) | Kb(120-136) | Pb(136-168); reused as act(104-168)
  // 168-184: VbT
  // 184-216: y (fp32; attn out, then FFN2 out)
  // 216+   : red (8 floats)
  bf16*  xb  = (bf16*)(ws);
  bf16*  hb  = xb;
  bf16*  WqT = (bf16*)(ws + 16 * MB);
  bf16*  WkT = (bf16*)(ws + 24 * MB);
  bf16*  WvT = (bf16*)(ws + 32 * MB);
  bf16*  W1T = (bf16*)(ws + 40 * MB);
  bf16*  W2T = (bf16*)(ws + 72 * MB);
  bf16*  Qb  = (bf16*)(ws + 104 * MB);
  bf16*  Kb  = (bf16*)(ws + 120 * MB);
  bf16*  Pb  = (bf16*)(ws + 136 * MB);
  bf16*  act = (bf16*)(ws + 104 * MB);
  bf16*  VbT = (bf16*)(ws + 168 * MB);
  float* y   = (float*)(ws + 184 * MB);
  float* red = (float*)(ws + 216 * MB);

  hipMemsetAsync(red, 0, 32, stream);

  const dim3 blk(256);
  const int nElemBlocks = (S * E) / 1024;

  cvt_f32_bf16<<<dim3(nElemBlocks), blk, 0, stream>>>(x, xb);
  transpose_cvt<<<dim3(E / 32, E / 32), blk, 0, stream>>>(Wq, WqT, E, E);
  transpose_cvt<<<dim3(E / 32, E / 32), blk, 0, stream>>>(Wk, WkT, E, E);
  transpose_cvt<<<dim3(E / 32, E / 32), blk, 0, stream>>>(Wv, WvT, E, E);
  transpose_cvt<<<dim3(H / 32, E / 32), blk, 0, stream>>>(W1, W1T, E, H);
  transpose_cvt<<<dim3(E / 32, H / 32), blk, 0, stream>>>(W2, W2T, H, E);

  // Q = x@Wq + bq, K = x@Wk + bk (bf16 out)
  gemm_bt<0><<<dim3(E / 128, S / 128), blk, 0, stream>>>(
      xb, E, WqT, E, Qb, nullptr, E, bq, nullptr, nullptr, nullptr, S, E, E, 0.f);
  gemm_bt<0><<<dim3(E / 128, S / 128), blk, 0, stream>>>(
      xb, E, WkT, E, Kb, nullptr, E, bk, nullptr, nullptr, nullptr, S, E, E, 0.f);
  // V^T[E,S] = WvT @ x^T + bv[row]
  gemm_bt<1><<<dim3(S / 128, E / 128), blk, 0, stream>>>(
      WvT, E, xb, E, VbT, nullptr, S, bv, nullptr, nullptr, nullptr, E, S, E, 0.f);

  // scores = (Q @ K^T)/64 -> bf16, softmax rows
  gemm_bt<2><<<dim3(S / 128, S / 128), blk, 0, stream>>>(
      Qb, E, Kb, E, Pb, nullptr, S, nullptr, nullptr, nullptr, nullptr, S, S, E, 1.0f / 64.0f);
  softmax_rows<<<dim3(S), blk, 0, stream>>>(Pb);

  // y = x + P @ V (fp32, fused LN1 sums)
  gemm_bt<3><<<dim3(E / 128, S / 128), blk, 0, stream>>>(
      Pb, S, VbT, S, nullptr, y, E, nullptr, x, nullptr, red, S, E, S, 0.f);
  ln_finalize<<<1, 1, 0, stream>>>(red, (float)((size_t)S * E));
  ln_apply<<<dim3(nElemBlocks), blk, 0, stream>>>(y, red, nullptr, hb);

  // act = relu(h @ W1 + b1) -> bf16
  gemm_bt<4><<<dim3(H / 128, S / 128), blk, 0, stream>>>(
      hb, E, W1T, E, act, nullptr, H, b1, nullptr, nullptr, nullptr, S, H, E, 0.f);

  // y = h + act @ W2 + b2 (fp32, fused LN2 sums)
  gemm_bt<5><<<dim3(E / 128, S / 128), blk, 0, stream>>>(
      act, H, W2T, H, nullptr, y, E, b2, nullptr, hb, red + 4, S, E, H, 0.f);
  ln_finalize<<<1, 1, 0, stream>>>(red + 4, (float)((size_t)S * E));
  ln_apply<<<dim3(nElemBlocks), blk, 0, stream>>>(y, red + 4, out, nullptr);
}